// Round 1
// baseline (333.665 us; speedup 1.0000x reference)
//
#include <hip/hip_runtime.h>
#include <math.h>

#define JN 4096
#define CN 8192
#define FN 64

// ---- workspace layout (float offsets) ----
#define WS_ROWSUM 0          // 4096
#define WS_DEG    4096       // 4096  (cols :J only)
#define WS_F1     8192       // 24576 (acc -> final f1)
#define WS_F2     32768      // 24576 (acc -> final f2)
#define WS_ZERO_FLOATS 57344 // everything above is atomically accumulated -> memset each launch
#define WS_NORM   57344      // 4096
#define WS_X      61440      // 24576
#define WS_XN     86016      // 24576
#define WS_F1N    110592     // 24576
#define WS_GT     135168     // 262144
#define WS_PART   397312     // 8192 (max,sum per value-block)
#define WS_GRES   405504     // 2

__global__ __launch_bounds__(256) void k_rowsum(const float* __restrict__ G, float* __restrict__ rowsum) {
    int i = blockIdx.x;
    const float4* row = (const float4*)(G + (size_t)i * CN);
    float s = 0.f;
    for (int k = threadIdx.x; k < CN / 4; k += 256) {
        float4 v = row[k];
        s += v.x + v.y + v.z + v.w;
    }
    for (int o = 32; o; o >>= 1) s += __shfl_down(s, o, 64);
    __shared__ float lds[4];
    int lane = threadIdx.x & 63, w = threadIdx.x >> 6;
    if (!lane) lds[w] = s;
    __syncthreads();
    if (!threadIdx.x) rowsum[i] = lds[0] + lds[1] + lds[2] + lds[3];
}

__global__ __launch_bounds__(256) void k_colsum(const float* __restrict__ G, float* __restrict__ deg) {
    int c = blockIdx.x * 256 + threadIdx.x;   // < 4096
    int r0 = blockIdx.y * 128;
    float s = 0.f;
    for (int r = 0; r < 128; ++r) s += G[(size_t)(r0 + r) * CN + c];
    atomicAdd(&deg[c], s);
}

__global__ __launch_bounds__(256) void k_norm(const float* __restrict__ deg, float* __restrict__ norm) {
    int j = blockIdx.x * 256 + threadIdx.x;
    if (j < JN) {
        float d = deg[j];
        d = d < 1.f ? 1.f : d;
        norm[j] = 1.0f / sqrtf(d);
    }
}

__global__ __launch_bounds__(256) void k_rank(const float* __restrict__ h, const float* __restrict__ L,
                                              const float* __restrict__ Wp, const float* __restrict__ Pp,
                                              const float* __restrict__ Np,
                                              const float* __restrict__ norm,
                                              float* __restrict__ X, float* __restrict__ Xn) {
    int i = blockIdx.x;
    float hi = h[i];
    int cnt = 0;
    for (int j = threadIdx.x; j < JN; j += 256) {
        float hj = h[j];
        cnt += (hj > hi) || (hj == hi && j < i);   // stable argsort(-h) rank
    }
    for (int o = 32; o; o >>= 1) cnt += __shfl_down(cnt, o, 64);
    __shared__ int lds[4];
    int lane = threadIdx.x & 63, w = threadIdx.x >> 6;
    if (!lane) lds[w] = cnt;
    __syncthreads();
    if (!threadIdx.x) {
        int r = lds[0] + lds[1] + lds[2] + lds[3];
        float n = norm[r];
        float x0 = hi, x1 = L[i], x2 = *Wp, x3 = *Pp, x4 = *Np, x5 = 1.f;
        float* xr = X + r * 6;
        xr[0] = x0; xr[1] = x1; xr[2] = x2; xr[3] = x3; xr[4] = x4; xr[5] = x5;
        float* xnr = Xn + r * 6;
        xnr[0] = x0 * n; xnr[1] = x1 * n; xnr[2] = x2 * n; xnr[3] = x3 * n; xnr[4] = x4 * n; xnr[5] = x5 * n;
    }
}

// out_acc[c][k] += sum_r G[r][c] * in6[r][k], c < 4096
__global__ __launch_bounds__(256) void k_prop(const float* __restrict__ G, const float* __restrict__ in6,
                                              float* __restrict__ out_acc) {
    __shared__ float s_in[128 * 6];
    int c = blockIdx.x * 256 + threadIdx.x;   // < 4096
    int r0 = blockIdx.y * 128;
    for (int t = threadIdx.x; t < 768; t += 256) s_in[t] = in6[r0 * 6 + t];
    __syncthreads();
    float a0 = 0, a1 = 0, a2 = 0, a3 = 0, a4 = 0, a5 = 0;
    for (int r = 0; r < 128; ++r) {
        float g = G[(size_t)(r0 + r) * CN + c];
        const float* x = &s_in[r * 6];
        a0 += g * x[0]; a1 += g * x[1]; a2 += g * x[2];
        a3 += g * x[3]; a4 += g * x[4]; a5 += g * x[5];
    }
    float* o = out_acc + c * 6;
    atomicAdd(&o[0], a0); atomicAdd(&o[1], a1); atomicAdd(&o[2], a2);
    atomicAdd(&o[3], a3); atomicAdd(&o[4], a4); atomicAdd(&o[5], a5);
}

__global__ __launch_bounds__(256) void k_fin1(float* __restrict__ f1, const float* __restrict__ norm,
                                              float* __restrict__ f1n) {
    int idx = blockIdx.x * 256 + threadIdx.x;  // < 24576
    float n = norm[idx / 6];
    float v = f1[idx] * n;
    f1[idx] = v;        // final f1
    f1n[idx] = v * n;   // f1 * norm (prop2 input)
}

__global__ __launch_bounds__(256) void k_fin2(float* __restrict__ f2, const float* __restrict__ norm) {
    int idx = blockIdx.x * 256 + threadIdx.x;
    f2[idx] *= norm[idx / 6];
}

__global__ __launch_bounds__(256) void k_gt(const float* __restrict__ X, const float* __restrict__ f1,
                                            const float* __restrict__ f2, const float* __restrict__ tw,
                                            const float* __restrict__ tb, float* __restrict__ Gt) {
    int idx = blockIdx.x * 256 + threadIdx.x;  // < JN*64
    int j = idx >> 6, f = idx & 63;
    float acc = tb[f];
    const float* x = X + j * 6;
    const float* a = f1 + j * 6;
    const float* b = f2 + j * 6;
#pragma unroll
    for (int k = 0; k < 6; ++k) acc += x[k] * tw[k * 64 + f];
#pragma unroll
    for (int k = 0; k < 6; ++k) acc += a[k] * tw[(k + 6) * 64 + f];
#pragma unroll
    for (int k = 0; k < 6; ++k) acc += b[k] * tw[(k + 12) * 64 + f];
    Gt[idx] = acc;
}

// Value = Gt[:J] @ lin_w + lin_b, fused with online-softmax partials over tmp
__global__ __launch_bounds__(256) void k_value(const float* __restrict__ Gt, const float* __restrict__ lw,
                                               const float* __restrict__ lb,
                                               const float* __restrict__ rowsum, const float* __restrict__ deg,
                                               float* __restrict__ Value, float* __restrict__ partials) {
    __shared__ float sW[64 * 128];
    __shared__ float sG[64 * 65];   // transposed [f][r], padded
    __shared__ float sRedM[4], sRedS[4];
    int j0 = blockIdx.y * 64, c0 = blockIdx.x * 128;
    for (int t = threadIdx.x; t < 4096; t += 256) {
        int r = t >> 6, f = t & 63;
        sG[f * 65 + r] = Gt[(size_t)(j0 + r) * 64 + f];
    }
    for (int t = threadIdx.x; t < 8192; t += 256) {
        int f = t >> 7, cc = t & 127;
        sW[f * 128 + cc] = lw[(size_t)f * CN + c0 + cc];
    }
    __syncthreads();

    int tc = threadIdx.x & 31;   // col group -> cols c0 + tc*4 .. +3
    int rb = threadIdx.x >> 5;   // 0..7 -> rows j0 + rb*8 .. +7
    float acc[8][4];
#pragma unroll
    for (int q = 0; q < 8; ++q)
#pragma unroll
        for (int u = 0; u < 4; ++u) acc[q][u] = 0.f;

    for (int f = 0; f < 64; ++f) {
        float4 w = *(const float4*)&sW[f * 128 + tc * 4];
        const float* gcol = &sG[f * 65 + rb * 8];
#pragma unroll
        for (int q = 0; q < 8; ++q) {
            float g = gcol[q];
            acc[q][0] += g * w.x; acc[q][1] += g * w.y;
            acc[q][2] += g * w.z; acc[q][3] += g * w.w;
        }
    }

    float4 bb = *(const float4*)&lb[c0 + tc * 4];
    float mx = -INFINITY, sm = 0.f;
#pragma unroll
    for (int q = 0; q < 8; ++q) {
        int row = j0 + rb * 8 + q;
        float rs_i = rowsum[row];
        float dg_i = deg[row];
        float4 v;
        v.x = acc[q][0] + bb.x; v.y = acc[q][1] + bb.y;
        v.z = acc[q][2] + bb.z; v.w = acc[q][3] + bb.w;
        *(float4*)&Value[(size_t)row * CN + c0 + tc * 4] = v;
        float vv[4] = {v.x, v.y, v.z, v.w};
#pragma unroll
        for (int u = 0; u < 4; ++u) {
            int col = c0 + tc * 4 + u;
            float om;
            if (col < JN) {
                bool m1 = ((rs_i + rowsum[col] + dg_i + deg[col]) == 0.0f) && (col > row);
                om = m1 ? 0.f : 1.f;
            } else {
                om = rs_i;
            }
            float t = vv[u] - om * 10000.f;
            if (t > mx) { sm = sm * expf(mx - t) + 1.f; mx = t; }
            else        { sm += expf(t - mx); }
        }
    }
    // block-combine (mx, sm)
    for (int o = 32; o; o >>= 1) {
        float om_ = __shfl_down(mx, o, 64);
        float os_ = __shfl_down(sm, o, 64);
        float nm = fmaxf(mx, om_);
        sm = sm * expf(mx - nm) + os_ * expf(om_ - nm);
        mx = nm;
    }
    int lane = threadIdx.x & 63, w = threadIdx.x >> 6;
    if (!lane) { sRedM[w] = mx; sRedS[w] = sm; }
    __syncthreads();
    if (!threadIdx.x) {
        float M = sRedM[0], S = sRedS[0];
        for (int i = 1; i < 4; ++i) {
            float nm = fmaxf(M, sRedM[i]);
            S = S * expf(M - nm) + sRedS[i] * expf(sRedM[i] - nm);
            M = nm;
        }
        int bid = blockIdx.y * gridDim.x + blockIdx.x;
        partials[2 * bid] = M;
        partials[2 * bid + 1] = S;
    }
}

__global__ __launch_bounds__(256) void k_reduce(const float* __restrict__ partials, float* __restrict__ gres) {
    float mx = -INFINITY, sm = 0.f;
    for (int i = threadIdx.x; i < 4096; i += 256) {
        float m = partials[2 * i], s = partials[2 * i + 1];
        float nm = fmaxf(mx, m);
        sm = sm * expf(mx - nm) + s * expf(m - nm);
        mx = nm;
    }
    for (int o = 32; o; o >>= 1) {
        float om_ = __shfl_down(mx, o, 64);
        float os_ = __shfl_down(sm, o, 64);
        float nm = fmaxf(mx, om_);
        sm = sm * expf(mx - nm) + os_ * expf(om_ - nm);
        mx = nm;
    }
    __shared__ float sRedM[4], sRedS[4];
    int lane = threadIdx.x & 63, w = threadIdx.x >> 6;
    if (!lane) { sRedM[w] = mx; sRedS[w] = sm; }
    __syncthreads();
    if (!threadIdx.x) {
        float M = sRedM[0], S = sRedS[0];
        for (int i = 1; i < 4; ++i) {
            float nm = fmaxf(M, sRedM[i]);
            S = S * expf(M - nm) + sRedS[i] * expf(sRedM[i] - nm);
            M = nm;
        }
        gres[0] = M;
        gres[1] = S;
    }
}

__global__ __launch_bounds__(256) void k_poss(const float* __restrict__ Value, const float* __restrict__ rowsum,
                                              const float* __restrict__ deg, const float* __restrict__ gres,
                                              float* __restrict__ Poss) {
    float gmax = gres[0];
    float ginv = 1.0f / gres[1];
    size_t total4 = (size_t)JN * CN / 4;
    for (size_t l = (size_t)blockIdx.x * blockDim.x + threadIdx.x; l < total4;
         l += (size_t)gridDim.x * blockDim.x) {
        size_t e = l * 4;
        int row = (int)(e >> 13);
        int col = (int)(e & 8191);
        float4 v = ((const float4*)Value)[l];
        float rs_i = rowsum[row], dg_i = deg[row];
        float vv[4] = {v.x, v.y, v.z, v.w};
        float out[4];
#pragma unroll
        for (int u = 0; u < 4; ++u) {
            int cu = col + u;
            float om;
            if (cu < JN) {
                bool m1 = ((rs_i + rowsum[cu] + dg_i + deg[cu]) == 0.0f) && (cu > row);
                om = m1 ? 0.f : 1.f;
            } else {
                om = rs_i;
            }
            float t = vv[u] - om * 10000.f;
            out[u] = expf(t - gmax) * ginv;
        }
        ((float4*)Poss)[l] = make_float4(out[0], out[1], out[2], out[3]);
    }
}

extern "C" void kernel_launch(void* const* d_in, const int* in_sizes, int n_in,
                              void* d_out, int out_size, void* d_ws, size_t ws_size,
                              hipStream_t stream) {
    const float* h    = (const float*)d_in[0];
    const float* L    = (const float*)d_in[1];
    const float* W    = (const float*)d_in[2];
    const float* P    = (const float*)d_in[3];
    const float* N    = (const float*)d_in[4];
    const float* G    = (const float*)d_in[5];
    const float* tw   = (const float*)d_in[6];
    const float* tb   = (const float*)d_in[7];
    const float* lw   = (const float*)d_in[8];
    const float* lb   = (const float*)d_in[9];

    float* ws = (float*)d_ws;
    float* rowsum = ws + WS_ROWSUM;
    float* deg    = ws + WS_DEG;
    float* f1     = ws + WS_F1;
    float* f2     = ws + WS_F2;
    float* norm   = ws + WS_NORM;
    float* X      = ws + WS_X;
    float* Xn     = ws + WS_XN;
    float* f1n    = ws + WS_F1N;
    float* Gt     = ws + WS_GT;
    float* part   = ws + WS_PART;
    float* gres   = ws + WS_GRES;

    float* Value = (float*)d_out;
    float* Poss  = Value + (size_t)JN * CN;

    // zero the atomically-accumulated buffers (rowsum, deg, f1, f2)
    hipMemsetAsync(d_ws, 0, WS_ZERO_FLOATS * sizeof(float), stream);

    k_rowsum<<<JN, 256, 0, stream>>>(G, rowsum);
    k_colsum<<<dim3(16, 32), 256, 0, stream>>>(G, deg);
    k_norm<<<16, 256, 0, stream>>>(deg, norm);
    k_rank<<<JN, 256, 0, stream>>>(h, L, W, P, N, norm, X, Xn);
    k_prop<<<dim3(16, 32), 256, 0, stream>>>(G, Xn, f1);
    k_fin1<<<96, 256, 0, stream>>>(f1, norm, f1n);
    k_prop<<<dim3(16, 32), 256, 0, stream>>>(G, f1n, f2);
    k_fin2<<<96, 256, 0, stream>>>(f2, norm);
    k_gt<<<1024, 256, 0, stream>>>(X, f1, f2, tw, tb, Gt);
    k_value<<<dim3(64, 64), 256, 0, stream>>>(Gt, lw, lb, rowsum, deg, Value, part);
    k_reduce<<<1, 256, 0, stream>>>(part, gres);
    k_poss<<<2048, 256, 0, stream>>>(Value, rowsum, deg, gres, Poss);
}

// Round 2
// 234.835 us; speedup vs baseline: 1.4208x; 1.4208x over previous
//
#include <hip/hip_runtime.h>
#include <math.h>

#define JN 4096
#define CN 8192
#define FN 64

typedef __attribute__((ext_vector_type(8))) short short8;
typedef __attribute__((ext_vector_type(4))) float f32x4;

// ---- d_ws layout (float offsets) -- total 135170 floats = 540 KB ----
#define WS_ROWSUM 0        // 4096
#define WS_DEG    4096     // 4096
#define WS_NORM   8192     // 4096
#define WS_X      12288    // 24576
#define WS_XN     36864    // 24576
#define WS_F1     61440    // 24576
#define WS_F1N    86016    // 24576
#define WS_F2     110592   // 24576
#define WS_GRES   135168   // 2

// ---- scratch inside the Poss half of d_out (float offsets within Poss) ----
// Poss is only written by the final kernel; everything here is fully
// rewritten every launch before being read -> deterministic.
#define PS_COLPART 0        // 16*4096
#define PS_P1      65536    // 16*24576
#define PS_P2      458752   // 16*24576
#define PS_GTB     851968   // bf16 4096*64  (131072 float slots)
#define PS_LWT     983040   // bf16 8192*64  (262144 float slots)
#define PS_PART    1245184  // 2*2048

__device__ __forceinline__ unsigned short f2bf(float x) {
    unsigned int u = __float_as_uint(x);
    u += 0x7fffu + ((u >> 16) & 1u);   // RNE
    return (unsigned short)(u >> 16);
}

// ---------------- row sums over full G (128 MiB HBM pass) ----------------
__global__ __launch_bounds__(256) void k_rowsum(const float* __restrict__ G, float* __restrict__ rowsum) {
    int i = blockIdx.x;
    const float4* row = (const float4*)(G + (size_t)i * CN);
    float s = 0.f;
    for (int k = threadIdx.x; k < CN / 4; k += 256) {
        float4 v = row[k];
        s += v.x + v.y + v.z + v.w;
    }
    for (int o = 32; o; o >>= 1) s += __shfl_down(s, o, 64);
    __shared__ float lds[4];
    int lane = threadIdx.x & 63, w = threadIdx.x >> 6;
    if (!lane) lds[w] = s;
    __syncthreads();
    if (!threadIdx.x) rowsum[i] = lds[0] + lds[1] + lds[2] + lds[3];
}

// ---------------- column sums (cols :J), non-atomic partials ----------------
__global__ __launch_bounds__(256) void k_colsum(const float* __restrict__ G, float* __restrict__ colpart) {
    int c = blockIdx.x * 256 + threadIdx.x;   // < 4096
    int r0 = blockIdx.y * 256;
    float s = 0.f;
    for (int r = 0; r < 256; ++r) s += G[(size_t)(r0 + r) * CN + c];
    colpart[(size_t)blockIdx.y * JN + c] = s;
}

__global__ __launch_bounds__(256) void k_normred(const float* __restrict__ colpart,
                                                 float* __restrict__ deg, float* __restrict__ norm) {
    int j = blockIdx.x * 256 + threadIdx.x;
    float d = 0.f;
    for (int ch = 0; ch < 16; ++ch) d += colpart[(size_t)ch * JN + j];
    deg[j] = d;
    float dc = d < 1.f ? 1.f : d;
    norm[j] = rsqrtf(dc);
}

// ---------------- rank (stable argsort(-h)) + build X, Xn ----------------
__global__ __launch_bounds__(256) void k_rank(const float* __restrict__ h, const float* __restrict__ L,
                                              const float* __restrict__ Wp, const float* __restrict__ Pp,
                                              const float* __restrict__ Np,
                                              const float* __restrict__ norm,
                                              float* __restrict__ X, float* __restrict__ Xn) {
    int i = blockIdx.x;
    float hi = h[i];
    int cnt = 0;
    for (int j = threadIdx.x; j < JN; j += 256) {
        float hj = h[j];
        cnt += (hj > hi) || (hj == hi && j < i);
    }
    for (int o = 32; o; o >>= 1) cnt += __shfl_down(cnt, o, 64);
    __shared__ int lds[4];
    int lane = threadIdx.x & 63, w = threadIdx.x >> 6;
    if (!lane) lds[w] = cnt;
    __syncthreads();
    if (!threadIdx.x) {
        int r = lds[0] + lds[1] + lds[2] + lds[3];
        float n = norm[r];
        float x0 = hi, x1 = L[i], x2 = *Wp, x3 = *Pp, x4 = *Np, x5 = 1.f;
        float* xr = X + r * 6;
        xr[0] = x0; xr[1] = x1; xr[2] = x2; xr[3] = x3; xr[4] = x4; xr[5] = x5;
        float* xnr = Xn + r * 6;
        xnr[0] = x0 * n; xnr[1] = x1 * n; xnr[2] = x2 * n; xnr[3] = x3 * n; xnr[4] = x4 * n; xnr[5] = x5 * n;
    }
}

// ------------- propagation partials: part[ch][c][k] (non-atomic) -------------
__global__ __launch_bounds__(256) void k_prop(const float* __restrict__ G, const float* __restrict__ in6,
                                              float* __restrict__ part) {
    __shared__ float s_in[256 * 6];
    int c = blockIdx.x * 256 + threadIdx.x;   // < 4096
    int r0 = blockIdx.y * 256;
    for (int t = threadIdx.x; t < 1536; t += 256) s_in[t] = in6[r0 * 6 + t];
    __syncthreads();
    float a0 = 0, a1 = 0, a2 = 0, a3 = 0, a4 = 0, a5 = 0;
    for (int r = 0; r < 256; ++r) {
        float g = G[(size_t)(r0 + r) * CN + c];
        const float* x = &s_in[r * 6];
        a0 += g * x[0]; a1 += g * x[1]; a2 += g * x[2];
        a3 += g * x[3]; a4 += g * x[4]; a5 += g * x[5];
    }
    float* o = part + ((size_t)blockIdx.y * JN + c) * 6;
    o[0] = a0; o[1] = a1; o[2] = a2; o[3] = a3; o[4] = a4; o[5] = a5;
}

__global__ __launch_bounds__(256) void k_fin1(const float* __restrict__ p1, const float* __restrict__ norm,
                                              float* __restrict__ f1, float* __restrict__ f1n) {
    int idx = blockIdx.x * 256 + threadIdx.x;  // < 24576
    float s = 0.f;
    for (int ch = 0; ch < 16; ++ch) s += p1[(size_t)ch * 24576 + idx];
    float n = norm[idx / 6];
    float v = s * n;
    f1[idx] = v;
    f1n[idx] = v * n;
}

__global__ __launch_bounds__(256) void k_fin2(const float* __restrict__ p2, const float* __restrict__ norm,
                                              float* __restrict__ f2) {
    int idx = blockIdx.x * 256 + threadIdx.x;
    float s = 0.f;
    for (int ch = 0; ch < 16; ++ch) s += p2[(size_t)ch * 24576 + idx];
    f2[idx] = s * norm[idx / 6];
}

// ---------------- G_t = [f0 f1 f2] @ tag_w + tag_b  ->  bf16 ----------------
__global__ __launch_bounds__(256) void k_gt(const float* __restrict__ X, const float* __restrict__ f1,
                                            const float* __restrict__ f2, const float* __restrict__ tw,
                                            const float* __restrict__ tb, unsigned short* __restrict__ Gtb) {
    int idx = blockIdx.x * 256 + threadIdx.x;  // < JN*64
    int j = idx >> 6, f = idx & 63;
    float acc = tb[f];
    const float* x = X + j * 6;
    const float* a = f1 + j * 6;
    const float* b = f2 + j * 6;
#pragma unroll
    for (int k = 0; k < 6; ++k) acc += x[k] * tw[k * 64 + f];
#pragma unroll
    for (int k = 0; k < 6; ++k) acc += a[k] * tw[(k + 6) * 64 + f];
#pragma unroll
    for (int k = 0; k < 6; ++k) acc += b[k] * tw[(k + 12) * 64 + f];
    Gtb[idx] = f2bf(acc);
}

// ---------------- lin_w (64x8192 f32) -> lwT (8192x64 bf16) ----------------
__global__ __launch_bounds__(256) void k_lwT(const float* __restrict__ lw, unsigned short* __restrict__ lwT) {
    __shared__ float s[64][65];
    int c0 = blockIdx.x * 64;
    for (int t = threadIdx.x; t < 4096; t += 256) {
        int f = t >> 6, cc = t & 63;
        s[f][cc] = lw[(size_t)f * CN + c0 + cc];
    }
    __syncthreads();
    for (int q = threadIdx.x; q < 512; q += 256) {
        int c = q >> 3, kc = q & 7;
        short8 pack;
#pragma unroll
        for (int i = 0; i < 8; ++i) pack[i] = (short)f2bf(s[kc * 8 + i][c]);
        *(short8*)(lwT + ((size_t)(c0 + c)) * 64 + kc * 8) = pack;
    }
}

// -------- Value = Gt @ lin_w + lin_b (bf16 MFMA, fp32 acc) + fused softmax --------
__global__ __launch_bounds__(256) void k_value(const unsigned short* __restrict__ Gtb,
                                               const unsigned short* __restrict__ lwT,
                                               const float* __restrict__ lb,
                                               const float* __restrict__ rowsum, const float* __restrict__ deg,
                                               float* __restrict__ Value, float* __restrict__ partials) {
    __shared__ unsigned short sA[64 * 64];    //  8 KB, XOR-swizzled
    __shared__ unsigned short sB[256 * 64];   // 32 KB, XOR-swizzled
    __shared__ float sRedM[4], sRedS[4];
    int j0 = blockIdx.y * 64;
    int c0 = blockIdx.x * 256;
    int tid = threadIdx.x;

    // stage A tile (64 rows x 64 k bf16), 16B chunks, swizzle byte^=(row&7)<<4
    for (int q = tid; q < 512; q += 256) {
        int row = q >> 3, off = q & 7;
        short8 v = *(const short8*)(Gtb + ((size_t)(j0 + row)) * 64 + off * 8);
        int byte = (row * 128 + off * 16) ^ ((row & 7) << 4);
        *(short8*)((char*)sA + byte) = v;
    }
    // stage B tile (256 cols x 64 k bf16)
    for (int q = tid; q < 2048; q += 256) {
        int col = q >> 3, off = q & 7;
        short8 v = *(const short8*)(lwT + ((size_t)(c0 + col)) * 64 + off * 8);
        int byte = (col * 128 + off * 16) ^ ((col & 7) << 4);
        *(short8*)((char*)sB + byte) = v;
    }
    __syncthreads();

    int lane = tid & 63, w = tid >> 6;
    int lrow = lane & 15;        // row-in-tile (A) / col-in-tile (B, C)
    int kg = lane >> 4;          // 0..3

    f32x4 acc[4][4];
#pragma unroll
    for (int m = 0; m < 4; ++m)
#pragma unroll
        for (int n = 0; n < 4; ++n) acc[m][n] = (f32x4){0.f, 0.f, 0.f, 0.f};

#pragma unroll
    for (int ks = 0; ks < 2; ++ks) {
        int kb = ks * 64 + kg * 16;   // byte offset of this lane's 8 bf16 along k
        short8 af[4], bfr[4];
#pragma unroll
        for (int m = 0; m < 4; ++m) {
            int row = m * 16 + lrow;
            int byte = (row * 128 + kb) ^ ((row & 7) << 4);
            af[m] = *(const short8*)((const char*)sA + byte);
        }
#pragma unroll
        for (int n = 0; n < 4; ++n) {
            int col = w * 64 + n * 16 + lrow;
            int byte = (col * 128 + kb) ^ ((col & 7) << 4);
            bfr[n] = *(const short8*)((const char*)sB + byte);
        }
#pragma unroll
        for (int m = 0; m < 4; ++m)
#pragma unroll
            for (int n = 0; n < 4; ++n)
                acc[m][n] = __builtin_amdgcn_mfma_f32_16x16x32_bf16(af[m], bfr[n], acc[m][n], 0, 0, 0);
    }

    // epilogue: bias + Value store + masked online-softmax partials
    bool left = (c0 < JN);
    int colbase = c0 + w * 64;
    float bn[4], rsc[4], dgc[4];
#pragma unroll
    for (int n = 0; n < 4; ++n) {
        int col = colbase + n * 16 + lrow;
        bn[n] = lb[col];
        if (left) { rsc[n] = rowsum[col]; dgc[n] = deg[col]; }
        else      { rsc[n] = 0.f; dgc[n] = 0.f; }
    }

    float mx = -INFINITY, sm = 0.f;
#pragma unroll
    for (int m = 0; m < 4; ++m) {
#pragma unroll
        for (int r = 0; r < 4; ++r) {
            int row = j0 + m * 16 + kg * 4 + r;
            float rs_i = rowsum[row];
            float dg_i = deg[row];
#pragma unroll
            for (int n = 0; n < 4; ++n) {
                int col = colbase + n * 16 + lrow;
                float v = acc[m][n][r] + bn[n];
                Value[(size_t)row * CN + col] = v;
                float om;
                if (left) {
                    bool m1 = ((rs_i + rsc[n] + dg_i + dgc[n]) == 0.0f) && (col > row);
                    om = m1 ? 0.f : 1.f;
                } else {
                    om = rs_i;
                }
                float t = v - om * 10000.f;
                float nm = fmaxf(mx, t);
                sm = sm * __expf(mx - nm) + __expf(t - nm);
                mx = nm;
            }
        }
    }

    for (int o = 32; o; o >>= 1) {
        float om_ = __shfl_down(mx, o, 64);
        float os_ = __shfl_down(sm, o, 64);
        float nm = fmaxf(mx, om_);
        sm = sm * __expf(mx - nm) + os_ * __expf(om_ - nm);
        mx = nm;
    }
    if (!lane) { sRedM[w] = mx; sRedS[w] = sm; }
    __syncthreads();
    if (!tid) {
        float M = sRedM[0], S = sRedS[0];
        for (int i = 1; i < 4; ++i) {
            float nm = fmaxf(M, sRedM[i]);
            S = S * __expf(M - nm) + sRedS[i] * __expf(sRedM[i] - nm);
            M = nm;
        }
        int bid = blockIdx.y * gridDim.x + blockIdx.x;   // < 2048
        partials[2 * bid] = M;
        partials[2 * bid + 1] = S;
    }
}

__global__ __launch_bounds__(256) void k_reduce(const float* __restrict__ partials, float* __restrict__ gres) {
    float mx = -INFINITY, sm = 0.f;
    for (int i = threadIdx.x; i < 2048; i += 256) {
        float m = partials[2 * i], s = partials[2 * i + 1];
        float nm = fmaxf(mx, m);
        sm = sm * __expf(mx - nm) + s * __expf(m - nm);
        mx = nm;
    }
    for (int o = 32; o; o >>= 1) {
        float om_ = __shfl_down(mx, o, 64);
        float os_ = __shfl_down(sm, o, 64);
        float nm = fmaxf(mx, om_);
        sm = sm * __expf(mx - nm) + os_ * __expf(om_ - nm);
        mx = nm;
    }
    __shared__ float sRedM[4], sRedS[4];
    int lane = threadIdx.x & 63, w = threadIdx.x >> 6;
    if (!lane) { sRedM[w] = mx; sRedS[w] = sm; }
    __syncthreads();
    if (!threadIdx.x) {
        float M = sRedM[0], S = sRedS[0];
        for (int i = 1; i < 4; ++i) {
            float nm = fmaxf(M, sRedM[i]);
            S = S * __expf(M - nm) + sRedS[i] * __expf(sRedM[i] - nm);
            M = nm;
        }
        gres[0] = M;
        gres[1] = S;
    }
}

__global__ __launch_bounds__(256) void k_poss(const float* __restrict__ Value, const float* __restrict__ rowsum,
                                              const float* __restrict__ deg, const float* __restrict__ gres,
                                              float* __restrict__ Poss) {
    float gmax = gres[0];
    float ginv = 1.0f / gres[1];
    size_t total4 = (size_t)JN * CN / 4;
    for (size_t l = (size_t)blockIdx.x * blockDim.x + threadIdx.x; l < total4;
         l += (size_t)gridDim.x * blockDim.x) {
        size_t e = l * 4;
        int row = (int)(e >> 13);
        int col = (int)(e & 8191);
        float4 v = ((const float4*)Value)[l];
        float rs_i = rowsum[row], dg_i = deg[row];
        float vv[4] = {v.x, v.y, v.z, v.w};
        float out[4];
#pragma unroll
        for (int u = 0; u < 4; ++u) {
            int cu = col + u;
            float om;
            if (cu < JN) {
                bool m1 = ((rs_i + rowsum[cu] + dg_i + deg[cu]) == 0.0f) && (cu > row);
                om = m1 ? 0.f : 1.f;
            } else {
                om = rs_i;
            }
            float t = vv[u] - om * 10000.f;
            out[u] = __expf(t - gmax) * ginv;
        }
        ((float4*)Poss)[l] = make_float4(out[0], out[1], out[2], out[3]);
    }
}

extern "C" void kernel_launch(void* const* d_in, const int* in_sizes, int n_in,
                              void* d_out, int out_size, void* d_ws, size_t ws_size,
                              hipStream_t stream) {
    const float* h  = (const float*)d_in[0];
    const float* L  = (const float*)d_in[1];
    const float* W  = (const float*)d_in[2];
    const float* P  = (const float*)d_in[3];
    const float* N  = (const float*)d_in[4];
    const float* G  = (const float*)d_in[5];
    const float* tw = (const float*)d_in[6];
    const float* tb = (const float*)d_in[7];
    const float* lw = (const float*)d_in[8];
    const float* lb = (const float*)d_in[9];

    float* ws = (float*)d_ws;
    float* rowsum = ws + WS_ROWSUM;
    float* deg    = ws + WS_DEG;
    float* norm   = ws + WS_NORM;
    float* X      = ws + WS_X;
    float* Xn     = ws + WS_XN;
    float* f1     = ws + WS_F1;
    float* f1n    = ws + WS_F1N;
    float* f2     = ws + WS_F2;
    float* gres   = ws + WS_GRES;

    float* Value = (float*)d_out;
    float* Poss  = Value + (size_t)JN * CN;

    // scratch carved out of the Poss half of d_out (fully rewritten each launch)
    float* colpart = Poss + PS_COLPART;
    float* p1      = Poss + PS_P1;
    float* p2      = Poss + PS_P2;
    unsigned short* Gtb = (unsigned short*)(Poss + PS_GTB);
    unsigned short* lwT = (unsigned short*)(Poss + PS_LWT);
    float* part    = Poss + PS_PART;

    k_lwT   <<<128, 256, 0, stream>>>(lw, lwT);
    k_rowsum<<<JN, 256, 0, stream>>>(G, rowsum);
    k_colsum<<<dim3(16, 16), 256, 0, stream>>>(G, colpart);
    k_normred<<<16, 256, 0, stream>>>(colpart, deg, norm);
    k_rank  <<<JN, 256, 0, stream>>>(h, L, W, P, N, norm, X, Xn);
    k_prop  <<<dim3(16, 16), 256, 0, stream>>>(G, Xn, p1);
    k_fin1  <<<96, 256, 0, stream>>>(p1, norm, f1, f1n);
    k_prop  <<<dim3(16, 16), 256, 0, stream>>>(G, f1n, p2);
    k_fin2  <<<96, 256, 0, stream>>>(p2, norm, f2);
    k_gt    <<<1024, 256, 0, stream>>>(X, f1, f2, tw, tb, Gtb);
    k_value <<<dim3(32, 64), 256, 0, stream>>>(Gtb, lwT, lb, rowsum, deg, Value, part);
    k_reduce<<<1, 256, 0, stream>>>(part, gres);
    k_poss  <<<2048, 256, 0, stream>>>(Value, rowsum, deg, gres, Poss);
}

// Round 3
// 203.480 us; speedup vs baseline: 1.6398x; 1.1541x over previous
//
#include <hip/hip_runtime.h>
#include <math.h>

#define JN 4096
#define CN 8192

typedef __attribute__((ext_vector_type(8))) short short8;
typedef __attribute__((ext_vector_type(4))) float f32x4;

// ---- d_ws layout (float offsets) -- total 397314 floats = 1.59 MB ----
#define WS_LWT    0        // bf16 8192*64 = 262144 float slots (16B-aligned)
#define WS_ROWSUM 262144   // 4096
#define WS_DEG    266240   // 4096
#define WS_NORM   270336   // 4096
#define WS_X      274432   // 24576
#define WS_XN     299008   // 24576
#define WS_F1     323584   // 24576
#define WS_F1N    348160   // 24576
#define WS_F2     372736   // 24576
#define WS_GRES   397312   // 2

// ---- scratch inside the Poss half of d_out (float offsets within Poss) ----
// All consumed before k_valueB overwrites the Poss region; k_valueB reads
// nothing from this region -> no race, deterministic.
#define PS_GTB     0        // bf16 4096*64 = 131072 float slots
#define PS_BITR    131072   // uint64[4096][64] = 2 MiB = 524288 float slots
#define PS_COLPART 655360   // 16*4096
#define PS_P1      720896   // 16*24576
#define PS_P2      1114112  // 16*24576
#define PS_PART    1507328  // 2*2048

__device__ __forceinline__ unsigned short f2bf(float x) {
    unsigned int u = __float_as_uint(x);
    u += 0x7fffu + ((u >> 16) & 1u);   // RNE
    return (unsigned short)(u >> 16);
}

// G_t(row, f) given row-vectors x (f0), a (f1), b (f2) and tag weights.
__device__ __forceinline__ float gt_val(const float* __restrict__ x, const float* __restrict__ a,
                                        const float* __restrict__ b, const float* __restrict__ tw,
                                        float acc, int f) {
#pragma unroll
    for (int k = 0; k < 6; ++k) acc += x[k] * tw[k * 64 + f];
#pragma unroll
    for (int k = 0; k < 6; ++k) acc += a[k] * tw[(k + 6) * 64 + f];
#pragma unroll
    for (int k = 0; k < 6; ++k) acc += b[k] * tw[(k + 12) * 64 + f];
    return acc;
}

// ---------- pass1: one full read of G -> rowsum + bit-packed left half ----------
__global__ __launch_bounds__(256) void k_pass1(const float* __restrict__ G, float* __restrict__ rowsum,
                                               unsigned long long* __restrict__ bitR) {
    int row = blockIdx.x;
    const float* r = G + (size_t)row * CN;
    int w = threadIdx.x >> 6, lane = threadIdx.x & 63;
    unsigned long long* brow = bitR + (size_t)row * 64;
    float s = 0.f;
    // left half (cols 0..4095): 64 words of 64 cols; wave w handles words [w*16, w*16+16)
    for (int j = w * 16; j < w * 16 + 16; ++j) {
        float g = r[j * 64 + lane];
        s += g;
        unsigned long long m = __ballot(g != 0.f);
        if (!lane) brow[j] = m;
    }
    // right half (cols 4096..8191): vectorized sum only
    const float4* r4 = (const float4*)(r + 4096);
    for (int k = threadIdx.x; k < 1024; k += 256) {
        float4 v = r4[k];
        s += v.x + v.y + v.z + v.w;
    }
    for (int o = 32; o; o >>= 1) s += __shfl_down(s, o, 64);
    __shared__ float lds[4];
    if (!lane) lds[w] = s;
    __syncthreads();
    if (!threadIdx.x) rowsum[row] = lds[0] + lds[1] + lds[2] + lds[3];
}

// ---------- column sums from bitmask ----------
__global__ __launch_bounds__(256) void k_colsum_bits(const unsigned long long* __restrict__ bitR,
                                                     float* __restrict__ colpart) {
    __shared__ unsigned long long s_bits[256][4];
    int c0 = blockIdx.x * 256, r0 = blockIdx.y * 256;
    int tid = threadIdx.x;
    int w0 = c0 >> 6;
    for (int t = tid; t < 1024; t += 256) {
        int r = t >> 2, wl = t & 3;
        s_bits[r][wl] = bitR[(size_t)(r0 + r) * 64 + w0 + wl];
    }
    __syncthreads();
    int wid = tid >> 6, lane = tid & 63;
    int cnt = 0;
    for (int r = 0; r < 256; ++r)
        cnt += (int)((s_bits[r][wid] >> lane) & 1ull);
    colpart[(size_t)blockIdx.y * JN + c0 + tid] = (float)cnt;
}

__global__ __launch_bounds__(256) void k_normred(const float* __restrict__ colpart,
                                                 float* __restrict__ deg, float* __restrict__ norm) {
    int j = blockIdx.x * 256 + threadIdx.x;
    float d = 0.f;
    for (int ch = 0; ch < 16; ++ch) d += colpart[(size_t)ch * JN + j];
    deg[j] = d;
    float dc = d < 1.f ? 1.f : d;
    norm[j] = rsqrtf(dc);
}

// ---------- rank (stable argsort(-h)) + build X, Xn ----------
__global__ __launch_bounds__(256) void k_rank(const float* __restrict__ h, const float* __restrict__ L,
                                              const float* __restrict__ Wp, const float* __restrict__ Pp,
                                              const float* __restrict__ Np,
                                              const float* __restrict__ norm,
                                              float* __restrict__ X, float* __restrict__ Xn) {
    int i = blockIdx.x;
    float hi = h[i];
    int cnt = 0;
    for (int j = threadIdx.x; j < JN; j += 256) {
        float hj = h[j];
        cnt += (hj > hi) || (hj == hi && j < i);
    }
    for (int o = 32; o; o >>= 1) cnt += __shfl_down(cnt, o, 64);
    __shared__ int lds[4];
    int lane = threadIdx.x & 63, w = threadIdx.x >> 6;
    if (!lane) lds[w] = cnt;
    __syncthreads();
    if (!threadIdx.x) {
        int r = lds[0] + lds[1] + lds[2] + lds[3];
        float n = norm[r];
        float x0 = hi, x1 = L[i], x2 = *Wp, x3 = *Pp, x4 = *Np, x5 = 1.f;
        float* xr = X + r * 6;
        xr[0] = x0; xr[1] = x1; xr[2] = x2; xr[3] = x3; xr[4] = x4; xr[5] = x5;
        float* xnr = Xn + r * 6;
        xnr[0] = x0 * n; xnr[1] = x1 * n; xnr[2] = x2 * n; xnr[3] = x3 * n; xnr[4] = x4 * n; xnr[5] = x5 * n;
    }
}

// ---------- propagation from bitmask: part[ch][c][k] ----------
__global__ __launch_bounds__(256) void k_prop_bits(const unsigned long long* __restrict__ bitR,
                                                   const float* __restrict__ in6, float* __restrict__ part) {
    __shared__ unsigned long long s_bits[256][4];
    __shared__ float s_in[256 * 6];
    int c0 = blockIdx.x * 256, r0 = blockIdx.y * 256;
    int tid = threadIdx.x;
    int w0 = c0 >> 6;
    for (int t = tid; t < 1024; t += 256) {
        int r = t >> 2, wl = t & 3;
        s_bits[r][wl] = bitR[(size_t)(r0 + r) * 64 + w0 + wl];
    }
    for (int t = tid; t < 1536; t += 256) s_in[t] = in6[r0 * 6 + t];
    __syncthreads();
    int wid = tid >> 6, lane = tid & 63;
    float a0 = 0, a1 = 0, a2 = 0, a3 = 0, a4 = 0, a5 = 0;
    for (int r = 0; r < 256; ++r) {
        float g = (float)((s_bits[r][wid] >> lane) & 1ull);
        const float* x = &s_in[r * 6];
        a0 += g * x[0]; a1 += g * x[1]; a2 += g * x[2];
        a3 += g * x[3]; a4 += g * x[4]; a5 += g * x[5];
    }
    float* o = part + ((size_t)blockIdx.y * JN + c0 + tid) * 6;
    o[0] = a0; o[1] = a1; o[2] = a2; o[3] = a3; o[4] = a4; o[5] = a5;
}

__global__ __launch_bounds__(256) void k_fin1(const float* __restrict__ p1, const float* __restrict__ norm,
                                              float* __restrict__ f1, float* __restrict__ f1n) {
    int idx = blockIdx.x * 256 + threadIdx.x;  // < 24576
    float s = 0.f;
    for (int ch = 0; ch < 16; ++ch) s += p1[(size_t)ch * 24576 + idx];
    float n = norm[idx / 6];
    float v = s * n;
    f1[idx] = v;
    f1n[idx] = v * n;
}

__global__ __launch_bounds__(256) void k_fin2(const float* __restrict__ p2, const float* __restrict__ norm,
                                              float* __restrict__ f2) {
    int idx = blockIdx.x * 256 + threadIdx.x;
    float s = 0.f;
    for (int ch = 0; ch < 16; ++ch) s += p2[(size_t)ch * 24576 + idx];
    f2[idx] = s * norm[idx / 6];
}

// ---------- G_t -> bf16 (for pass A) ----------
__global__ __launch_bounds__(256) void k_gt(const float* __restrict__ X, const float* __restrict__ f1,
                                            const float* __restrict__ f2, const float* __restrict__ tw,
                                            const float* __restrict__ tb, unsigned short* __restrict__ Gtb) {
    int idx = blockIdx.x * 256 + threadIdx.x;  // < JN*64
    int j = idx >> 6, f = idx & 63;
    float acc = gt_val(X + j * 6, f1 + j * 6, f2 + j * 6, tw, tb[f], f);
    Gtb[idx] = f2bf(acc);
}

// ---------- lin_w (64x8192 f32) -> lwT (8192x64 bf16) ----------
__global__ __launch_bounds__(256) void k_lwT(const float* __restrict__ lw, unsigned short* __restrict__ lwT) {
    __shared__ float s[64][65];
    int c0 = blockIdx.x * 64;
    for (int t = threadIdx.x; t < 4096; t += 256) {
        int f = t >> 6, cc = t & 63;
        s[f][cc] = lw[(size_t)f * CN + c0 + cc];
    }
    __syncthreads();
    for (int q = threadIdx.x; q < 512; q += 256) {
        int c = q >> 3, kc = q & 7;
        short8 pack;
#pragma unroll
        for (int i = 0; i < 8; ++i) pack[i] = (short)f2bf(s[kc * 8 + i][c]);
        *(short8*)(lwT + ((size_t)(c0 + c)) * 64 + kc * 8) = pack;
    }
}

// ---------- pass A: Value = Gt @ lin_w + lin_b (bf16 MFMA) + softmax partials ----------
__global__ __launch_bounds__(256) void k_valueA(const unsigned short* __restrict__ Gtb,
                                                const unsigned short* __restrict__ lwT,
                                                const float* __restrict__ lb,
                                                const float* __restrict__ rowsum, const float* __restrict__ deg,
                                                float* __restrict__ Value, float* __restrict__ partials) {
    __shared__ unsigned short sA[64 * 64];
    __shared__ unsigned short sB[256 * 64];
    __shared__ float sRedM[4], sRedS[4];
    int j0 = blockIdx.y * 64;
    int c0 = blockIdx.x * 256;
    int tid = threadIdx.x;

    for (int q = tid; q < 512; q += 256) {
        int row = q >> 3, off = q & 7;
        short8 v = *(const short8*)(Gtb + ((size_t)(j0 + row)) * 64 + off * 8);
        int byte = (row * 128 + off * 16) ^ ((row & 7) << 4);
        *(short8*)((char*)sA + byte) = v;
    }
    for (int q = tid; q < 2048; q += 256) {
        int col = q >> 3, off = q & 7;
        short8 v = *(const short8*)(lwT + ((size_t)(c0 + col)) * 64 + off * 8);
        int byte = (col * 128 + off * 16) ^ ((col & 7) << 4);
        *(short8*)((char*)sB + byte) = v;
    }
    __syncthreads();

    int lane = tid & 63, w = tid >> 6;
    int lrow = lane & 15;
    int kg = lane >> 4;

    f32x4 acc[4][4];
#pragma unroll
    for (int m = 0; m < 4; ++m)
#pragma unroll
        for (int n = 0; n < 4; ++n) acc[m][n] = (f32x4){0.f, 0.f, 0.f, 0.f};

#pragma unroll
    for (int ks = 0; ks < 2; ++ks) {
        int kb = ks * 64 + kg * 16;
        short8 af[4], bfr[4];
#pragma unroll
        for (int m = 0; m < 4; ++m) {
            int row = m * 16 + lrow;
            int byte = (row * 128 + kb) ^ ((row & 7) << 4);
            af[m] = *(const short8*)((const char*)sA + byte);
        }
#pragma unroll
        for (int n = 0; n < 4; ++n) {
            int col = w * 64 + n * 16 + lrow;
            int byte = (col * 128 + kb) ^ ((col & 7) << 4);
            bfr[n] = *(const short8*)((const char*)sB + byte);
        }
#pragma unroll
        for (int m = 0; m < 4; ++m)
#pragma unroll
            for (int n = 0; n < 4; ++n)
                acc[m][n] = __builtin_amdgcn_mfma_f32_16x16x32_bf16(af[m], bfr[n], acc[m][n], 0, 0, 0);
    }

    bool left = (c0 < JN);
    int colbase = c0 + w * 64;
    float bn[4], rsc[4], dgc[4];
#pragma unroll
    for (int n = 0; n < 4; ++n) {
        int col = colbase + n * 16 + lrow;
        bn[n] = lb[col];
        if (left) { rsc[n] = rowsum[col]; dgc[n] = deg[col]; }
        else      { rsc[n] = 0.f; dgc[n] = 0.f; }
    }

    float mx = -INFINITY, sm = 0.f;
#pragma unroll
    for (int m = 0; m < 4; ++m) {
#pragma unroll
        for (int r = 0; r < 4; ++r) {
            int row = j0 + m * 16 + kg * 4 + r;
            float rs_i = rowsum[row];
            float dg_i = deg[row];
#pragma unroll
            for (int n = 0; n < 4; ++n) {
                int col = colbase + n * 16 + lrow;
                float v = acc[m][n][r] + bn[n];
                Value[(size_t)row * CN + col] = v;
                float om;
                if (left) {
                    bool m1 = ((rs_i + rsc[n] + dg_i + dgc[n]) == 0.0f) && (col > row);
                    om = m1 ? 0.f : 1.f;
                } else {
                    om = rs_i;
                }
                float t = v - om * 10000.f;
                float nm = fmaxf(mx, t);
                sm = sm * __expf(mx - nm) + __expf(t - nm);
                mx = nm;
            }
        }
    }

    for (int o = 32; o; o >>= 1) {
        float om_ = __shfl_down(mx, o, 64);
        float os_ = __shfl_down(sm, o, 64);
        float nm = fmaxf(mx, om_);
        sm = sm * __expf(mx - nm) + os_ * __expf(om_ - nm);
        mx = nm;
    }
    if (!lane) { sRedM[w] = mx; sRedS[w] = sm; }
    __syncthreads();
    if (!tid) {
        float M = sRedM[0], S = sRedS[0];
        for (int i = 1; i < 4; ++i) {
            float nm = fmaxf(M, sRedM[i]);
            S = S * __expf(M - nm) + sRedS[i] * __expf(sRedM[i] - nm);
            M = nm;
        }
        int bid = blockIdx.y * gridDim.x + blockIdx.x;
        partials[2 * bid] = M;
        partials[2 * bid + 1] = S;
    }
}

__global__ __launch_bounds__(256) void k_reduce(const float* __restrict__ partials, float* __restrict__ gres) {
    float mx = -INFINITY, sm = 0.f;
    for (int i = threadIdx.x; i < 2048; i += 256) {
        float m = partials[2 * i], s = partials[2 * i + 1];
        float nm = fmaxf(mx, m);
        sm = sm * __expf(mx - nm) + s * __expf(m - nm);
        mx = nm;
    }
    for (int o = 32; o; o >>= 1) {
        float om_ = __shfl_down(mx, o, 64);
        float os_ = __shfl_down(sm, o, 64);
        float nm = fmaxf(mx, om_);
        sm = sm * __expf(mx - nm) + os_ * __expf(om_ - nm);
        mx = nm;
    }
    __shared__ float sRedM[4], sRedS[4];
    int lane = threadIdx.x & 63, w = threadIdx.x >> 6;
    if (!lane) { sRedM[w] = mx; sRedS[w] = sm; }
    __syncthreads();
    if (!threadIdx.x) {
        float M = sRedM[0], S = sRedS[0];
        for (int i = 1; i < 4; ++i) {
            float nm = fmaxf(M, sRedM[i]);
            S = S * __expf(M - nm) + sRedS[i] * __expf(sRedM[i] - nm);
            M = nm;
        }
        gres[0] = M;
        gres[1] = S;
    }
}

// ---------- pass B: recompute GEMM, write Poss directly (no Value re-read) ----------
// Reads ONLY d_ws + raw inputs; writes the Poss region -> race-free vs PS scratch.
__global__ __launch_bounds__(256) void k_valueB(const float* __restrict__ X, const float* __restrict__ f1,
                                                const float* __restrict__ f2, const float* __restrict__ tw,
                                                const float* __restrict__ tb,
                                                const unsigned short* __restrict__ lwT,
                                                const float* __restrict__ lb,
                                                const float* __restrict__ rowsum, const float* __restrict__ deg,
                                                const float* __restrict__ gres, float* __restrict__ Poss) {
    __shared__ unsigned short sA[64 * 64];
    __shared__ unsigned short sB[256 * 64];
    __shared__ float s_tw[18 * 64];
    __shared__ float s_tb[64];
    int j0 = blockIdx.y * 64;
    int c0 = blockIdx.x * 256;
    int tid = threadIdx.x;

    for (int t = tid; t < 1152; t += 256) s_tw[t] = tw[t];
    if (tid < 64) s_tb[tid] = tb[tid];
    for (int q = tid; q < 2048; q += 256) {
        int col = q >> 3, off = q & 7;
        short8 v = *(const short8*)(lwT + ((size_t)(c0 + col)) * 64 + off * 8);
        int byte = (col * 128 + off * 16) ^ ((col & 7) << 4);
        *(short8*)((char*)sB + byte) = v;
    }
    __syncthreads();

    // recompute Gt rows j0..j0+63 -> bf16, swizzled into sA
    {
        int row = tid & 63, fg = tid >> 6;
        const float* xr = X + (size_t)(j0 + row) * 6;
        const float* ar = f1 + (size_t)(j0 + row) * 6;
        const float* br = f2 + (size_t)(j0 + row) * 6;
        float xv[6], av[6], bv[6];
#pragma unroll
        for (int k = 0; k < 6; ++k) { xv[k] = xr[k]; av[k] = ar[k]; bv[k] = br[k]; }
        short8 p0, p1v;
#pragma unroll
        for (int i = 0; i < 16; ++i) {
            int f = fg * 16 + i;
            float acc = gt_val(xv, av, bv, s_tw, s_tb[f], f);
            unsigned short u = f2bf(acc);
            if (i < 8) p0[i] = (short)u; else p1v[i - 8] = (short)u;
        }
        int base = row * 128 + fg * 32;
        *(short8*)((char*)sA + (base ^ ((row & 7) << 4))) = p0;
        *(short8*)((char*)sA + ((base + 16) ^ ((row & 7) << 4))) = p1v;
    }
    __syncthreads();

    int lane = tid & 63, w = tid >> 6;
    int lrow = lane & 15;
    int kg = lane >> 4;

    f32x4 acc[4][4];
#pragma unroll
    for (int m = 0; m < 4; ++m)
#pragma unroll
        for (int n = 0; n < 4; ++n) acc[m][n] = (f32x4){0.f, 0.f, 0.f, 0.f};

#pragma unroll
    for (int ks = 0; ks < 2; ++ks) {
        int kb = ks * 64 + kg * 16;
        short8 af[4], bfr[4];
#pragma unroll
        for (int m = 0; m < 4; ++m) {
            int row = m * 16 + lrow;
            int byte = (row * 128 + kb) ^ ((row & 7) << 4);
            af[m] = *(const short8*)((const char*)sA + byte);
        }
#pragma unroll
        for (int n = 0; n < 4; ++n) {
            int col = w * 64 + n * 16 + lrow;
            int byte = (col * 128 + kb) ^ ((col & 7) << 4);
            bfr[n] = *(const short8*)((const char*)sB + byte);
        }
#pragma unroll
        for (int m = 0; m < 4; ++m)
#pragma unroll
            for (int n = 0; n < 4; ++n)
                acc[m][n] = __builtin_amdgcn_mfma_f32_16x16x32_bf16(af[m], bfr[n], acc[m][n], 0, 0, 0);
    }

    bool left = (c0 < JN);
    int colbase = c0 + w * 64;
    float gmax = gres[0];
    float ginv = 1.0f / gres[1];
    float bn[4], rsc[4], dgc[4];
#pragma unroll
    for (int n = 0; n < 4; ++n) {
        int col = colbase + n * 16 + lrow;
        bn[n] = lb[col];
        if (left) { rsc[n] = rowsum[col]; dgc[n] = deg[col]; }
        else      { rsc[n] = 0.f; dgc[n] = 0.f; }
    }

#pragma unroll
    for (int m = 0; m < 4; ++m) {
#pragma unroll
        for (int r = 0; r < 4; ++r) {
            int row = j0 + m * 16 + kg * 4 + r;
            float rs_i = rowsum[row];
            float dg_i = deg[row];
#pragma unroll
            for (int n = 0; n < 4; ++n) {
                int col = colbase + n * 16 + lrow;
                float v = acc[m][n][r] + bn[n];
                float om;
                if (left) {
                    bool m1 = ((rs_i + rsc[n] + dg_i + dgc[n]) == 0.0f) && (col > row);
                    om = m1 ? 0.f : 1.f;
                } else {
                    om = rs_i;
                }
                float t = v - om * 10000.f;
                Poss[(size_t)row * CN + col] = __expf(t - gmax) * ginv;
            }
        }
    }
}

extern "C" void kernel_launch(void* const* d_in, const int* in_sizes, int n_in,
                              void* d_out, int out_size, void* d_ws, size_t ws_size,
                              hipStream_t stream) {
    const float* h  = (const float*)d_in[0];
    const float* L  = (const float*)d_in[1];
    const float* W  = (const float*)d_in[2];
    const float* P  = (const float*)d_in[3];
    const float* N  = (const float*)d_in[4];
    const float* G  = (const float*)d_in[5];
    const float* tw = (const float*)d_in[6];
    const float* tb = (const float*)d_in[7];
    const float* lw = (const float*)d_in[8];
    const float* lb = (const float*)d_in[9];

    float* ws = (float*)d_ws;
    unsigned short* lwT = (unsigned short*)(ws + WS_LWT);
    float* rowsum = ws + WS_ROWSUM;
    float* deg    = ws + WS_DEG;
    float* norm   = ws + WS_NORM;
    float* X      = ws + WS_X;
    float* Xn     = ws + WS_XN;
    float* f1     = ws + WS_F1;
    float* f1n    = ws + WS_F1N;
    float* f2     = ws + WS_F2;
    float* gres   = ws + WS_GRES;

    float* Value = (float*)d_out;
    float* Poss  = Value + (size_t)JN * CN;

    unsigned short* Gtb = (unsigned short*)(Poss + PS_GTB);
    unsigned long long* bitR = (unsigned long long*)(Poss + PS_BITR);
    float* colpart = Poss + PS_COLPART;
    float* p1      = Poss + PS_P1;
    float* p2      = Poss + PS_P2;
    float* part    = Poss + PS_PART;

    k_lwT        <<<128, 256, 0, stream>>>(lw, lwT);
    k_pass1      <<<JN, 256, 0, stream>>>(G, rowsum, bitR);
    k_colsum_bits<<<dim3(16, 16), 256, 0, stream>>>(bitR, colpart);
    k_normred    <<<16, 256, 0, stream>>>(colpart, deg, norm);
    k_rank       <<<JN, 256, 0, stream>>>(h, L, W, P, N, norm, X, Xn);
    k_prop_bits  <<<dim3(16, 16), 256, 0, stream>>>(bitR, Xn, p1);
    k_fin1       <<<96, 256, 0, stream>>>(p1, norm, f1, f1n);
    k_prop_bits  <<<dim3(16, 16), 256, 0, stream>>>(bitR, f1n, p2);
    k_fin2       <<<96, 256, 0, stream>>>(p2, norm, f2);
    k_gt         <<<1024, 256, 0, stream>>>(X, f1, f2, tw, tb, Gtb);
    k_valueA     <<<dim3(32, 64), 256, 0, stream>>>(Gtb, lwT, lb, rowsum, deg, Value, part);
    k_reduce     <<<1, 256, 0, stream>>>(part, gres);
    k_valueB     <<<dim3(32, 64), 256, 0, stream>>>(X, f1, f2, tw, tb, lwT, lb, rowsum, deg, gres, Poss);
}